// Round 2
// baseline (397.878 us; speedup 1.0000x reference)
//
#include <hip/hip_runtime.h>

typedef unsigned int u32;

// Derive the packed-half vector type from the builtin itself so pack,
// bit-casts and fdot2 all agree (clang may use __fp16 or _Float16 here).
using half2v = decltype(__builtin_amdgcn_cvt_pkrtz(0.f, 0.f));

__device__ inline u32 h2u(half2v h) { return __builtin_bit_cast(u32, h); }
__device__ inline half2v u2h(u32 u) { return __builtin_bit_cast(half2v, u); }

template <int CTRL>
__device__ inline float dppf(float x) {
  return __builtin_bit_cast(
      float, __builtin_amdgcn_update_dpp(0, __builtin_bit_cast(int, x), CTRL,
                                         0xF, 0xF, true));
}

__device__ inline float rlane(float v, int l) {
  return __builtin_bit_cast(
      float, __builtin_amdgcn_readlane(__builtin_bit_cast(int, v), l));
}

#if __has_builtin(__builtin_amdgcn_fdot2)
__device__ inline float fdot2f(half2v a, half2v b, float c) {
  return __builtin_amdgcn_fdot2(a, b, c, false);
}
#else
__device__ inline float fdot2f(half2v a, half2v b, float c) {
  return c + (float)a.x * (float)b.x + (float)a.y * (float)b.y;
}
#endif

// sum within each 16-lane row via DPP rotations (VALU pipe, not LDS)
__device__ inline float row16_sum(float v) {
  v += dppf<0x121>(v);  // row_ror:1
  v += dppf<0x122>(v);  // row_ror:2
  v += dppf<0x124>(v);  // row_ror:4
  v += dppf<0x128>(v);  // row_ror:8
  return v;
}

// softmax helpers over 8 consecutive lanes: quad_perm xor1, xor2, then
// row_half_mirror (valid as xor4 once 4-groups are uniform)
__device__ inline float max8(float v) {
  v = fmaxf(v, dppf<0xB1>(v));
  v = fmaxf(v, dppf<0x4E>(v));
  v = fmaxf(v, dppf<0x141>(v));
  return v;
}
__device__ inline float sum8(float v) {
  v += dppf<0xB1>(v);
  v += dppf<0x4E>(v);
  v += dppf<0x141>(v);
  return v;
}

// B blocks (one per batch row), 512 threads.
// LDS: z as fp16x2, 512 rows x 32 dwords, 16B-chunk index XOR-swizzled by
// (row&7) so row reads (p-phase b128) and column reads (u-phase b32) are
// both conflict-free. ~69 KiB total -> 2 blocks/CU on gfx950 (160 KiB).
__global__ __launch_bounds__(512, 4) void hete_attn(
    const float* __restrict__ feat, const float* __restrict__ mp,
    float* __restrict__ outp) {
  __shared__ u32 z_lds[512 * 32];   // 64 KiB normalized z, fp16 pairs
  __shared__ u32 u_lds[8 * 36];     // u fp16 pairs, row stride 36 dw (144B)
  __shared__ float p_lds[64 * 9 + 4];

  const int t = threadIdx.x;
  const int b = blockIdx.x;

  // ---- stage x: threads 0..255 load float2, l2norm per facet (32-lane
  // half-wave), keep fp32 in registers, seed u_lds with fp16 ----
  float2 xreg = make_float2(0.f, 0.f);
  if (t < 256) {
    const float2* xg = (const float2*)(feat + (size_t)b * 512);
    float2 xv = xg[t];
    float ss = row16_sum(xv.x * xv.x + xv.y * xv.y);
    ss += __shfl_xor(ss, 16);
    float sc = 1.0f / fmaxf(sqrtf(ss), 1e-12f);
    xreg.x = xv.x * sc;
    xreg.y = xv.y * sc;
    int f = t >> 5, d2 = t & 31;
    u_lds[f * 36 + d2] = h2u(__builtin_amdgcn_cvt_pkrtz(xreg.x, xreg.y));
  }

  // ---- stage z: coalesced float4 loads, per-row (16-lane group) sumsq via
  // DPP, normalize, pack fp16, swizzled ds_write_b64 ----
  {
    const float4* zg = (const float4*)(mp + (size_t)b * 32768);
    for (int hv = 0; hv < 2; hv++) {
      float4 v[8];
#pragma unroll
      for (int j = 0; j < 8; j++) v[j] = zg[(hv * 8 + j) * 512 + t];
#pragma unroll
      for (int j = 0; j < 8; j++) {
        int i = hv * 8 + j;
        float4 q = v[j];
        float ss = row16_sum(q.x * q.x + q.y * q.y + q.z * q.z + q.w * q.w);
        float sc = 1.0f / fmaxf(sqrtf(ss), 1e-12f);
        half2v h0 = __builtin_amdgcn_cvt_pkrtz(q.x * sc, q.y * sc);
        half2v h1 = __builtin_amdgcn_cvt_pkrtz(q.z * sc, q.w * sc);
        int row = i * 32 + (t >> 4);
        int c4 = t & 15;
        int dw = row * 32 + ((((c4 >> 1) ^ (row & 7)) << 2) + ((c4 & 1) << 1));
        uint2 pk;
        pk.x = h2u(h0);
        pk.y = h2u(h1);
        *(uint2*)&z_lds[dw] = pk;
      }
    }
  }
  __syncthreads();

  const int fq = t & 7;    // p-phase facet
  const int nq = t >> 3;   // p-phase neighbor
  const int uf = t >> 5;   // u-phase facet (t<256)
  const int d2 = t & 31;   // u-phase d-pair
  const int lane = t & 63;

  for (int it = 0; it < 3; it++) {
    // ---- p-phase: thread t owns (n,f); fdot2 over 64 dims ----
    {
      float acc = 0.f;
      const u32* zrow = &z_lds[t * 32];
      const u32* urow = &u_lds[fq * 36];
#pragma unroll
      for (int c = 0; c < 8; c++) {
        uint4 zq = *(const uint4*)(zrow + ((c ^ fq) << 2));
        uint4 uq = *(const uint4*)(urow + (c << 2));
        acc = fdot2f(u2h(zq.x), u2h(uq.x), acc);
        acc = fdot2f(u2h(zq.y), u2h(uq.y), acc);
        acc = fdot2f(u2h(zq.z), u2h(uq.z), acc);
        acc = fdot2f(u2h(zq.w), u2h(uq.w), acc);
      }
      float m = max8(acc);
      float e = __expf(acc - m);
      float s = sum8(e);
      p_lds[nq * 9 + fq] = e / s;
    }
    __syncthreads();

    // ---- u-phase: threads 0..255 own (f, d-pair); sum over 64 neighbors ----
    if (t < 256) {
      float pA = p_lds[lane * 9 + (uf & 6)];  // p[lane][2w]
      float pB = p_lds[lane * 9 + (uf | 1)];  // p[lane][2w+1]
      float2 acc2 = xreg;
      const u32* zc = &z_lds[uf * 32 + ((((d2 >> 2) ^ uf) << 2) + (d2 & 3))];
      const bool lo = lane < 32;
#pragma unroll 8
      for (int n = 0; n < 64; n++) {
        half2v hz = u2h(zc[n << 8]);
        float pf = lo ? rlane(pA, n) : rlane(pB, n);
        acc2.x += (float)hz.x * pf;
        acc2.y += (float)hz.y * pf;
      }
      if (it < 2) {
        float ss = row16_sum(acc2.x * acc2.x + acc2.y * acc2.y);
        ss += __shfl_xor(ss, 16);
        float sc = 1.0f / fmaxf(sqrtf(ss), 1e-12f);
        u_lds[uf * 36 + d2] =
            h2u(__builtin_amdgcn_cvt_pkrtz(acc2.x * sc, acc2.y * sc));
      } else {
        *(float2*)&outp[((size_t)b << 9) + (uf << 6) + (d2 << 1)] = acc2;
      }
    }
    __syncthreads();
  }
}

extern "C" void kernel_launch(void* const* d_in, const int* in_sizes, int n_in,
                              void* d_out, int out_size, void* d_ws,
                              size_t ws_size, hipStream_t stream) {
  const float* feat = (const float*)d_in[0];
  const float* mp = (const float*)d_in[1];
  float* outp = (float*)d_out;
  int B = in_sizes[0] / 512;  // 2048
  hete_attn<<<B, 512, 0, stream>>>(feat, mp, outp);
}

// Round 3
// 365.604 us; speedup vs baseline: 1.0883x; 1.0883x over previous
//
#include <hip/hip_runtime.h>

typedef unsigned int u32;

// Derive the packed-half vector type from the builtin itself so pack,
// bit-casts and fdot2 all agree (clang may use __fp16 or _Float16 here).
using half2v = decltype(__builtin_amdgcn_cvt_pkrtz(0.f, 0.f));

__device__ inline u32 h2u(half2v h) { return __builtin_bit_cast(u32, h); }
__device__ inline half2v u2h(u32 u) { return __builtin_bit_cast(half2v, u); }

template <int CTRL>
__device__ inline float dppf(float x) {
  return __builtin_bit_cast(
      float, __builtin_amdgcn_update_dpp(0, __builtin_bit_cast(int, x), CTRL,
                                         0xF, 0xF, true));
}

#if __has_builtin(__builtin_amdgcn_fdot2)
__device__ inline float fdot2f(half2v a, half2v b, float c) {
  return __builtin_amdgcn_fdot2(a, b, c, false);
}
#else
__device__ inline float fdot2f(half2v a, half2v b, float c) {
  return c + (float)a.x * (float)b.x + (float)a.y * (float)b.y;
}
#endif

// sum within each 16-lane row via DPP rotations (VALU pipe, not LDS)
__device__ inline float row16_sum(float v) {
  v += dppf<0x121>(v);  // row_ror:1
  v += dppf<0x122>(v);  // row_ror:2
  v += dppf<0x124>(v);  // row_ror:4
  v += dppf<0x128>(v);  // row_ror:8
  return v;
}

// reductions over 8 adjacent lanes: quad_perm xor1, xor2, then
// row_half_mirror (acts as xor4 once 4-groups are uniform)
__device__ inline float max8(float v) {
  v = fmaxf(v, dppf<0xB1>(v));
  v = fmaxf(v, dppf<0x4E>(v));
  v = fmaxf(v, dppf<0x141>(v));
  return v;
}
__device__ inline float sum8(float v) {
  v += dppf<0xB1>(v);
  v += dppf<0x4E>(v);
  v += dppf<0x141>(v);
  return v;
}

// One block per batch row, 512 threads.
// z_lds: 512 rows (row = n*8+f) x 32 dw of fp16 pairs, 16B chunks XOR-
// swizzled by (row&7)==f. p_lds transposed [f][n] for vector u-phase reads.
// ~69.5 KiB -> 2 blocks/CU.
__global__ __launch_bounds__(512, 4) void hete_attn(
    const float* __restrict__ feat, const float* __restrict__ mp,
    float* __restrict__ outp) {
  __shared__ u32 z_lds[512 * 32];   // 64 KiB normalized z, fp16 pairs
  __shared__ u32 u_lds[8 * 36];     // u fp16 pairs, row stride 36 dw
  __shared__ float p_lds[8 * 72];   // p transposed [f][n], stride 72
  __shared__ float x_lds[512];      // normalized x, fp32

  const int t = threadIdx.x;
  const int b = blockIdx.x;

  // ---- stage x: threads 0..255, l2norm per facet (32-lane half-wave) ----
  if (t < 256) {
    const float2* xg = (const float2*)(feat + (size_t)b * 512);
    float2 xv = xg[t];
    float ss = row16_sum(xv.x * xv.x + xv.y * xv.y);
    ss += __shfl_xor(ss, 16);
    float sc = 1.0f / fmaxf(sqrtf(ss), 1e-12f);
    float x0 = xv.x * sc, x1 = xv.y * sc;
    x_lds[2 * t] = x0;
    x_lds[2 * t + 1] = x1;
    u_lds[(t >> 5) * 36 + (t & 31)] = h2u(__builtin_amdgcn_cvt_pkrtz(x0, x1));
  }

  // ---- stage z: coalesced float4 loads, per-row (16-lane group) sumsq via
  // DPP, normalize, pack fp16, swizzled ds_write_b64 ----
  {
    const float4* zg = (const float4*)(mp + (size_t)b * 32768);
    for (int hv = 0; hv < 2; hv++) {
      float4 v[8];
#pragma unroll
      for (int j = 0; j < 8; j++) v[j] = zg[(hv * 8 + j) * 512 + t];
#pragma unroll
      for (int j = 0; j < 8; j++) {
        int i = hv * 8 + j;
        float4 q = v[j];
        float ss = row16_sum(q.x * q.x + q.y * q.y + q.z * q.z + q.w * q.w);
        float sc = 1.0f / fmaxf(sqrtf(ss), 1e-12f);
        half2v h0 = __builtin_amdgcn_cvt_pkrtz(q.x * sc, q.y * sc);
        half2v h1 = __builtin_amdgcn_cvt_pkrtz(q.z * sc, q.w * sc);
        int row = i * 32 + (t >> 4);
        int c4 = t & 15;
        int dw = row * 32 + ((((c4 >> 1) ^ (row & 7)) << 2) + ((c4 & 1) << 1));
        uint2 pk;
        pk.x = h2u(h0);
        pk.y = h2u(h1);
        *(uint2*)&z_lds[dw] = pk;
      }
    }
  }
  __syncthreads();

  const int fq = t & 7;   // p-phase facet
  const int nq = t >> 3;  // p-phase neighbor

  // u-phase mapping: all 512 threads
  const int uf = t >> 6;        // facet (wave-uniform)
  const int uc = (t >> 3) & 7;  // 4-dw chunk (dims 8*uc..8*uc+7)
  const int ug = t & 7;         // neighbor group: n = ug*8+k

  // ---- register-cache this thread's z row (n=nq, f=fq): 8 x b128 ----
  uint4 zrow[8];
  {
    const u32* zrowp = &z_lds[t * 32];
#pragma unroll
    for (int c = 0; c < 8; c++)
      zrow[c] = *(const uint4*)(zrowp + ((c ^ fq) << 2));
  }

  const u32* zcolp = &z_lds[ug * 2048 + uf * 32 + ((uc ^ uf) << 2)];
  const float* pcolp = &p_lds[uf * 72 + ug * 8];
  const float* xp = &x_lds[uf * 64 + uc * 8];

  for (int it = 0; it < 3; it++) {
    // ---- p-phase: thread (n,f); fdot2 over 64 dims from registers ----
    {
      const u32* urow = &u_lds[fq * 36];
      float acc = 0.f;
#pragma unroll
      for (int c = 0; c < 8; c++) {
        uint4 uq = *(const uint4*)(urow + (c << 2));
        acc = fdot2f(u2h(zrow[c].x), u2h(uq.x), acc);
        acc = fdot2f(u2h(zrow[c].y), u2h(uq.y), acc);
        acc = fdot2f(u2h(zrow[c].z), u2h(uq.z), acc);
        acc = fdot2f(u2h(zrow[c].w), u2h(uq.w), acc);
      }
      float m = max8(acc);
      float e = __expf(acc - m);
      float s = sum8(e);
      p_lds[fq * 72 + nq] = e / s;
    }
    __syncthreads();

    // ---- u-phase: thread (f, chunk, ngroup); 8 neighbors via b128 ----
    {
      float pk[8];
      *(float4*)&pk[0] = *(const float4*)(pcolp);
      *(float4*)&pk[4] = *(const float4*)(pcolp + 4);
      float acc[8] = {0.f, 0.f, 0.f, 0.f, 0.f, 0.f, 0.f, 0.f};
#pragma unroll
      for (int k = 0; k < 8; k++) {
        uint4 zq = *(const uint4*)(zcolp + (k << 8));
        half2v h0 = u2h(zq.x), h1 = u2h(zq.y), h2 = u2h(zq.z), h3 = u2h(zq.w);
        float p = pk[k];
        acc[0] += (float)h0.x * p;
        acc[1] += (float)h0.y * p;
        acc[2] += (float)h1.x * p;
        acc[3] += (float)h1.y * p;
        acc[4] += (float)h2.x * p;
        acc[5] += (float)h2.y * p;
        acc[6] += (float)h3.x * p;
        acc[7] += (float)h3.y * p;
      }
      // reduce over the 8 neighbor-groups (8 adjacent lanes)
#pragma unroll
      for (int j = 0; j < 8; j++) acc[j] = sum8(acc[j]);
      // add normalized x
      float4 xa = *(const float4*)(xp);
      float4 xb = *(const float4*)(xp + 4);
      acc[0] += xa.x; acc[1] += xa.y; acc[2] += xa.z; acc[3] += xa.w;
      acc[4] += xb.x; acc[5] += xb.y; acc[6] += xb.z; acc[7] += xb.w;

      if (it < 2) {
        float ss = 0.f;
#pragma unroll
        for (int j = 0; j < 8; j++) ss += acc[j] * acc[j];
        // wave covers one facet; every value replicated 8x over ug
        ss = row16_sum(ss);
        ss += __shfl_xor(ss, 16);
        ss += __shfl_xor(ss, 32);
        float sc = 1.0f / fmaxf(sqrtf(ss * 0.125f), 1e-12f);
        if (ug == 0) {
          uint4 o;
          o.x = h2u(__builtin_amdgcn_cvt_pkrtz(acc[0] * sc, acc[1] * sc));
          o.y = h2u(__builtin_amdgcn_cvt_pkrtz(acc[2] * sc, acc[3] * sc));
          o.z = h2u(__builtin_amdgcn_cvt_pkrtz(acc[4] * sc, acc[5] * sc));
          o.w = h2u(__builtin_amdgcn_cvt_pkrtz(acc[6] * sc, acc[7] * sc));
          *(uint4*)&u_lds[uf * 36 + (uc << 2)] = o;
        }
      } else {
        if (ug == 0) {
          float* op = &outp[((size_t)b << 9) + (uf << 6) + (uc << 3)];
          float4 o1 = {acc[0], acc[1], acc[2], acc[3]};
          float4 o2 = {acc[4], acc[5], acc[6], acc[7]};
          *(float4*)op = o1;
          *(float4*)(op + 4) = o2;
        }
      }
    }
    __syncthreads();
  }
}

extern "C" void kernel_launch(void* const* d_in, const int* in_sizes, int n_in,
                              void* d_out, int out_size, void* d_ws,
                              size_t ws_size, hipStream_t stream) {
  const float* feat = (const float*)d_in[0];
  const float* mp = (const float*)d_in[1];
  float* outp = (float*)d_out;
  int B = in_sizes[0] / 512;  // 2048
  hete_attn<<<B, 512, 0, stream>>>(feat, mp, outp);
}